// Round 3
// baseline (36.005 us; speedup 1.0000x reference)
//
#include <hip/hip_runtime.h>
#include <hip/hip_bf16.h>

#define EPS 1e-5f

// Fully fused: slice + LayerNorm + dot(W) + bias + sigmoid, single pass.
// logit = rs*(sum(x*gw) - mu*sum(gw)) + sum(beta*W) + bias,  gw = gamma*W
//
// Persistent grid: exactly 2048 blocks (8 blocks/CU x 256 CU = full residency
// in ONE dispatch round), each block owns 32 consecutive rows (2 chunks of 16).
// Per-block prologue (gw[768] + 2 consts into LDS) runs once per resident
// block, concurrently across the whole machine, amortized over 2x the rows.
__global__ __launch_bounds__(256) void head_kernel(
    const float* __restrict__ x, const float* __restrict__ gamma,
    const float* __restrict__ beta, const float* __restrict__ W,
    const float* __restrict__ bias, float* __restrict__ out) {
    __shared__ float s_gw[768];
    __shared__ float s_red[8];
    __shared__ float s_c[2];

    const int t = threadIdx.x;

    // ---- per-block prologue: gw into LDS + consts (gamma/beta/W are L2-hot) ----
    {
        float sgw = 0.f, sbw = 0.f;
#pragma unroll
        for (int i = t; i < 768; i += 256) {
            float w  = W[i];
            float gv = gamma[i] * w;
            s_gw[i] = gv;
            sgw += gv;
            sbw += beta[i] * w;
        }
#pragma unroll
        for (int m = 32; m; m >>= 1) {
            sgw += __shfl_xor(sgw, m);
            sbw += __shfl_xor(sbw, m);
        }
        const int wv = t >> 6;
        if ((t & 63) == 0) { s_red[wv * 2] = sgw; s_red[wv * 2 + 1] = sbw; }
        __syncthreads();
        if (t == 0) {
            s_c[0] = s_red[0] + s_red[2] + s_red[4] + s_red[6];
            s_c[1] = s_red[1] + s_red[3] + s_red[5] + s_red[7] + bias[0];
        }
        __syncthreads();
    }

    // ---- main: 32 rows/block = 2 chunks x (4 waves x 4 rows); 16 lanes/row ----
    const int lane  = t & 63;
    const int wv    = t >> 6;
    const int sl    = lane & 15;   // sub-lane within the row's 16-lane group
    const int grp   = lane >> 4;   // which of the wave's 4 rows
    const int rbase = blockIdx.x * 32 + wv * 4 + grp;
    const float inv_e = 1.0f / 768.0f;

#pragma unroll
    for (int c = 0; c < 2; ++c) {
        const int row = rbase + c * 16;              // 0 .. 65535
        const int b   = row >> 8;
        const int n   = row & 255;
        const float* __restrict__ xr = x + (size_t)(b * 257 + n + 1) * 768;

        float s1 = 0.f, s2 = 0.f, s3 = 0.f;
#pragma unroll
        for (int k = 0; k < 12; ++k) {
            const int idx = sl * 4 + k * 64;  // 16 lanes x float4 = 256B/group
            float4 v = *reinterpret_cast<const float4*>(xr + idx);
            float4 w = *reinterpret_cast<const float4*>(s_gw + idx);
            s1 += v.x + v.y + v.z + v.w;
            s2 += v.x * v.x + v.y * v.y + v.z * v.z + v.w * v.w;
            s3 += v.x * w.x + v.y * w.y + v.z * w.z + v.w * w.w;
        }
        // butterfly over the 16-lane group: reduces the wave's 4 rows at once
#pragma unroll
        for (int m = 8; m; m >>= 1) {
            s1 += __shfl_xor(s1, m);
            s2 += __shfl_xor(s2, m);
            s3 += __shfl_xor(s3, m);
        }
        if (sl == 0) {
            float mu  = s1 * inv_e;
            float var = s2 * inv_e - mu * mu;
            float rs  = rsqrtf(var + EPS);
            float logit = rs * (s3 - mu * s_c[0]) + s_c[1];
            out[row] = 1.0f / (1.0f + __expf(-logit));
        }
    }
}

extern "C" void kernel_launch(void* const* d_in, const int* in_sizes, int n_in,
                              void* d_out, int out_size, void* d_ws, size_t ws_size,
                              hipStream_t stream) {
    const float* x     = (const float*)d_in[0];   // (256, 257, 768)
    const float* gamma = (const float*)d_in[1];   // (768,)
    const float* beta  = (const float*)d_in[2];   // (768,)
    const float* W     = (const float*)d_in[3];   // (1, 768)
    const float* bias  = (const float*)d_in[4];   // (1,)
    float* out = (float*)d_out;                   // 65536 floats

    head_kernel<<<2048, 256, 0, stream>>>(x, gamma, beta, W, bias, out);
}